// Round 12
// baseline (512.761 us; speedup 1.0000x reference)
//
#include <hip/hip_runtime.h>

#define N_PTS 200000
#define C_IN  32
#define C_OUT 64
#define K_NB  27
#define BN_EPS 1e-5f
#define CBLK  3125     // conv grid: 64 points per block

using bf16x8 = __attribute__((ext_vector_type(8))) short;
using f32x4  = __attribute__((ext_vector_type(4))) float;

typedef const __attribute__((address_space(1))) char GP;
typedef __attribute__((address_space(3))) char LP;

// ---------------- ws layout (MFMA paths) ----------------
//  [0, 114688)           wt   : bf16[28][64][32]  (row 27 zeros)
//  [114688, +4096)       sums8: float[8][128]     (banked BN atomics)
//  [118784, +4)          cnt  : uint              (block-done counter)
//  [119040, +512)        ab   : float[128]        (a[64], b[64])
//  [131072, +1.6MB)      ps   : (spare)
//  [2097152, +12.8MB)    xt   : bf16[N+1][32]     (row N = zeros)
//  [14897216, +25.6MB)   raw16: fp16[64][N]       (config A only)
#define M_WT_OFF   0
#define M_SUM_OFF  114688
#define M_CNT_OFF  118784
#define M_AB_OFF   119040
#define M_XT_OFF   2097152
#define M_RAW_OFF  14897216
#define M_WS_NEED_B ((size_t)M_XT_OFF + (size_t)(N_PTS + 1) * C_IN * 2)          // 14,897,216
#define M_WS_NEED_A ((size_t)M_RAW_OFF + (size_t)C_OUT * N_PTS * 2)              // 40,497,216

// ---------------- ws layout (fallback f32 path) ----------------
#define F_WTK_OFF 0
#define F_AB_OFF  221184
#define F_PS_OFF  221824

__device__ __forceinline__ unsigned short f2bf(float f) {
    unsigned int u = __float_as_uint(f);
    u = (u + 0x7fffu + ((u >> 16) & 1u)) >> 16;
    return (unsigned short)u;
}
__device__ __forceinline__ unsigned short f2h(float f) {
    _Float16 h = (_Float16)f;
    unsigned short u; __builtin_memcpy(&u, &h, 2); return u;
}
__device__ __forceinline__ float h2f(unsigned short u) {
    _Float16 h; __builtin_memcpy(&h, &u, 2); return (float)h;
}

// ---------- prep: blocks [0,782): x->xt bf16 (+zero row); [782,1006): w->wt ----------
__global__ void k_prep(const float* __restrict__ x, const float* __restrict__ w,
                       unsigned short* __restrict__ xt, unsigned short* __restrict__ wt) {
    if (blockIdx.x < 782) {
        int n = blockIdx.x * 256 + threadIdx.x;
        if (n > N_PTS) return;
        unsigned short row[C_IN];
        if (n == N_PTS) {
#pragma unroll
            for (int c = 0; c < C_IN; ++c) row[c] = 0;
        } else {
#pragma unroll
            for (int c = 0; c < C_IN; ++c) row[c] = f2bf(x[(long long)c * N_PTS + n]);
        }
        uint4* dst = (uint4*)(xt + (long long)n * C_IN);
#pragma unroll
        for (int q = 0; q < 4; ++q) dst[q] = ((const uint4*)row)[q];
    } else {
        int i = (blockIdx.x - 782) * 256 + threadIdx.x;
        if (i >= 28 * C_OUT * C_IN) return;
        int c = i & 31, o = (i >> 5) & 63, k = i >> 11;
        wt[i] = (k < K_NB) ? f2bf(w[(o * C_IN + c) * K_NB + k]) : (unsigned short)0;
    }
}

// ---------- one 64-point chunk: verified R7/R10 pipeline, acc[4] result ----------
__device__ __forceinline__ void conv_chunk(int n0, const char* xtb,
                                           const int* __restrict__ neigh,
                                           const unsigned short* wtA, unsigned qoff,
                                           unsigned badr, unsigned tadr,
                                           char* bufB, int* ntb, int w, f32x4 acc[4]) {
    {
        int p  = threadIdx.x & 63;
        int kb = (threadIdx.x >> 6) * 7;        // 0,7,14,21
        const int* nrow = neigh + (long long)(n0 + p) * K_NB;
#pragma unroll
        for (int i = 0; i < 7; ++i) {
            int kk = kb + i;
            if (kk < K_NB) {
                int t = nrow[kk];
                ntb[kk * 64 + p] = ((unsigned)t < N_PTS) ? t : N_PTS;
            }
        }
    }
    __syncthreads();

    acc[0] = f32x4{0.f,0.f,0.f,0.f}; acc[1] = f32x4{0.f,0.f,0.f,0.f};
    acc[2] = f32x4{0.f,0.f,0.f,0.f}; acc[3] = f32x4{0.f,0.f,0.f,0.f};
    bf16x8 Ar[4];
    int tcur;

#define PSTEP(KK) \
    asm volatile("ds_read_b32 %0, %1 offset:%2" : "=v"(tcur) : "v"(tadr), "i"((KK)*256)); \
    asm volatile("s_waitcnt lgkmcnt(0)" ::: "memory"); \
    __builtin_amdgcn_sched_barrier(0); \
    __builtin_amdgcn_global_load_lds((GP*)(xtb + (unsigned long long)(unsigned)tcur * 64ull + qoff), \
        (LP*)(bufB + (KK)*4096 + w*1024), 16, 0, 0); \
    asm volatile("global_load_dwordx4 %0, %1, off" : "=v"(Ar[(KK)&3]) : "v"(wtA + (KK)*2048)); \
    __builtin_amdgcn_sched_barrier(0);

    PSTEP(0) PSTEP(1) PSTEP(2) PSTEP(3)
#undef PSTEP
    asm volatile("ds_read_b32 %0, %1 offset:%2" : "=v"(tcur) : "v"(tadr), "i"(4*256));

#define STEP(K, VM, PF, NT, LG) { \
    if (PF) { \
        asm volatile("s_waitcnt lgkmcnt(0)" ::: "memory"); \
        __builtin_amdgcn_sched_barrier(0); \
        __builtin_amdgcn_global_load_lds((GP*)(xtb + (unsigned long long)(unsigned)tcur * 64ull + qoff), \
            (LP*)(bufB + (((K)+4)%6)*4096 + w*1024), 16, 0, 0); \
    } \
    __builtin_amdgcn_sched_barrier(0); \
    asm volatile("s_waitcnt vmcnt(%0)" :: "i"(VM) : "memory"); \
    __builtin_amdgcn_sched_barrier(0); \
    asm volatile("s_barrier" ::: "memory"); \
    __builtin_amdgcn_sched_barrier(0); \
    bf16x8 b0, b1, b2, b3; \
    asm volatile("ds_read_b128 %0, %1 offset:%2" : "=v"(b0) : "v"(badr), "i"(((K)%6)*4096 + 0)); \
    asm volatile("ds_read_b128 %0, %1 offset:%2" : "=v"(b1) : "v"(badr), "i"(((K)%6)*4096 + 1024)); \
    asm volatile("ds_read_b128 %0, %1 offset:%2" : "=v"(b2) : "v"(badr), "i"(((K)%6)*4096 + 2048)); \
    asm volatile("ds_read_b128 %0, %1 offset:%2" : "=v"(b3) : "v"(badr), "i"(((K)%6)*4096 + 3072)); \
    if (NT) { asm volatile("ds_read_b32 %0, %1 offset:%2" : "=v"(tcur) : "v"(tadr), "i"(((K)+5)*256)); } \
    asm volatile("s_waitcnt lgkmcnt(%0)" :: "i"(LG) : "memory"); \
    __builtin_amdgcn_sched_barrier(0); \
    acc[0] = __builtin_amdgcn_mfma_f32_16x16x32_bf16(Ar[(K)&3], b0, acc[0], 0, 0, 0); \
    acc[1] = __builtin_amdgcn_mfma_f32_16x16x32_bf16(Ar[(K)&3], b1, acc[1], 0, 0, 0); \
    acc[2] = __builtin_amdgcn_mfma_f32_16x16x32_bf16(Ar[(K)&3], b2, acc[2], 0, 0, 0); \
    acc[3] = __builtin_amdgcn_mfma_f32_16x16x32_bf16(Ar[(K)&3], b3, acc[3], 0, 0, 0); \
    if (PF) { \
        asm volatile("global_load_dwordx4 %0, %1, off" : "=v"(Ar[((K)+4)&3]) : "v"(wtA + ((K)+4)*2048)); \
    } \
    __builtin_amdgcn_sched_barrier(0); \
}

    STEP(0,7,1,1,1)  STEP(1,7,1,1,1)  STEP(2,7,1,1,1)  STEP(3,7,1,1,1)
    STEP(4,7,1,1,1)  STEP(5,7,1,1,1)  STEP(6,7,1,1,1)  STEP(7,7,1,1,1)
    STEP(8,7,1,1,1)  STEP(9,7,1,1,1)  STEP(10,7,1,1,1) STEP(11,7,1,1,1)
    STEP(12,7,1,1,1) STEP(13,7,1,1,1) STEP(14,7,1,1,1) STEP(15,7,1,1,1)
    STEP(16,7,1,1,1) STEP(17,7,1,1,1) STEP(18,7,1,1,1) STEP(19,7,1,1,1)
    STEP(20,7,1,1,1) STEP(21,7,1,1,1) STEP(22,7,1,0,0)
    STEP(23,6,0,0,0) STEP(24,4,0,0,0) STEP(25,2,0,0,0) STEP(26,0,0,0,0)
#undef STEP

    asm volatile("s_waitcnt vmcnt(0) lgkmcnt(0)" ::: "memory");
    __builtin_amdgcn_sched_barrier(0);
}

// ---------- conv + banked atomic BN stats + last-block finisher -> ab ----------
// RAW16=1: raw conv out as fp16 into raw16[]; RAW16=0: f32 into out[].
template <int RAW16>
__launch_bounds__(256, 5)
__global__ void k_conv_mfma(const unsigned short* __restrict__ xt,
                            const int* __restrict__ neigh,
                            const unsigned short* __restrict__ wt,
                            float* __restrict__ out,
                            unsigned short* __restrict__ raw16,
                            const float* __restrict__ gam,
                            const float* __restrict__ bet,
                            float* __restrict__ sums8,
                            unsigned* __restrict__ cnt,
                            float* __restrict__ ab) {
    __shared__ __align__(16) char lds_raw[6 * 4096 + K_NB * 64 * 4];
    __shared__ int fin;
    char* bufB = lds_raw;
    int*  ntb  = (int*)(lds_raw + 24576);
    const int lane = threadIdx.x & 63;
    const int w    = threadIdx.x >> 6;
    const int l15  = lane & 15, lq = lane >> 4;
    const int n0   = blockIdx.x * 64;

    const char* xtb = (const char*)xt;
    const unsigned short* wtA = wt + w * 512 + l15 * 32 + lq * 8;
    const unsigned qoff = (unsigned)(lq * 16);
    unsigned bufB_a = (unsigned)(unsigned long long)(LP*)lds_raw;
    unsigned ntb_a  = bufB_a + 24576;
    unsigned badr   = bufB_a + (unsigned)(lq * 256 + l15 * 16);
    unsigned tadr   = ntb_a + (unsigned)(w * 64 + l15 * 4);

    f32x4 acc[4];
    conv_chunk(n0, xtb, neigh, wtA, qoff, badr, tadr, bufB, ntb, w, acc);

    // ---- raw output: och = 16w + lq*4 + r, point = n0 + g*16 + l15 ----
    if (RAW16) {
#pragma unroll
        for (int r = 0; r < 4; ++r) {
            unsigned short* o = raw16 + (long long)(16 * w + lq * 4 + r) * N_PTS + n0 + l15;
            o[0]  = f2h(acc[0][r]);
            o[16] = f2h(acc[1][r]);
            o[32] = f2h(acc[2][r]);
            o[48] = f2h(acc[3][r]);
        }
    } else {
#pragma unroll
        for (int r = 0; r < 4; ++r) {
            float* o = out + (long long)(16 * w + lq * 4 + r) * N_PTS + n0 + l15;
            o[0]  = acc[0][r];
            o[16] = acc[1][r];
            o[32] = acc[2][r];
            o[48] = acc[3][r];
        }
    }

    // ---- BN partials -> banked device atomics ----
    f32x4 s  = acc[0] + acc[1] + acc[2] + acc[3];
    f32x4 sq = acc[0]*acc[0] + acc[1]*acc[1] + acc[2]*acc[2] + acc[3]*acc[3];
#pragma unroll
    for (int d = 1; d < 16; d <<= 1) {
#pragma unroll
        for (int r = 0; r < 4; ++r) {
            s[r]  += __shfl_xor(s[r], d);
            sq[r] += __shfl_xor(sq[r], d);
        }
    }
    if (l15 == 0) {
        int bank = (blockIdx.x & 7) * 128;
#pragma unroll
        for (int r = 0; r < 4; ++r) {
            int ch = 16 * w + lq * 4 + r;
            atomicAdd(&sums8[bank + ch],      s[r]);
            atomicAdd(&sums8[bank + 64 + ch], sq[r]);
        }
    }
    __threadfence();
    __syncthreads();
    if (threadIdx.x == 0) {
        unsigned old = atomicAdd(cnt, 1u);
        fin = (old == CBLK - 1) ? 1 : 0;
    }
    __syncthreads();
    if (fin) {
        // last block: reduce 8 banks -> a,b  (atomic reads for device-scope coherence)
        int t = threadIdx.x;
        if (t < 64) {
            float S = 0.f, S2 = 0.f;
#pragma unroll
            for (int b = 0; b < 8; ++b) {
                S  += atomicAdd(&sums8[b * 128 + t], 0.f);
                S2 += atomicAdd(&sums8[b * 128 + 64 + t], 0.f);
            }
            float mean = S / (float)N_PTS;
            float var  = S2 / (float)N_PTS - mean * mean;
            float a = gam[t] * rsqrtf(var + BN_EPS);
            float b = bet[t] - mean * a;
            ab[t]      = a;
            ab[64 + t] = b;
        }
    }
}

// ---------- normalize + relu from fp16 raw -> f32 out (config A) ----------
__global__ void k_norm16(const unsigned short* __restrict__ raw16, float* __restrict__ out,
                         const float* __restrict__ ab) {
    int i = blockIdx.x * 256 + threadIdx.x;        // ushort8 units
    const int tot8 = (C_OUT * N_PTS) / 8;
    if (i >= tot8) return;
    int o = (int)(((long long)i * 8) / N_PTS);
    float a = ab[o], b = ab[64 + o];
    union { uint4 u4; unsigned short us[8]; } U;
    U.u4 = ((const uint4*)raw16)[i];
    float4 r0, r1;
    r0.x = fmaxf(fmaf(h2f(U.us[0]), a, b), 0.f);
    r0.y = fmaxf(fmaf(h2f(U.us[1]), a, b), 0.f);
    r0.z = fmaxf(fmaf(h2f(U.us[2]), a, b), 0.f);
    r0.w = fmaxf(fmaf(h2f(U.us[3]), a, b), 0.f);
    r1.x = fmaxf(fmaf(h2f(U.us[4]), a, b), 0.f);
    r1.y = fmaxf(fmaf(h2f(U.us[5]), a, b), 0.f);
    r1.z = fmaxf(fmaf(h2f(U.us[6]), a, b), 0.f);
    r1.w = fmaxf(fmaf(h2f(U.us[7]), a, b), 0.f);
    ((float4*)out)[2 * i]     = r0;
    ((float4*)out)[2 * i + 1] = r1;
}

// ---------- normalize + relu, in place on d_out (config B) ----------
__global__ void k_norm(float* __restrict__ out, const float* __restrict__ ab) {
    int i = blockIdx.x * 256 + threadIdx.x;
    const int total4 = (C_OUT * N_PTS) / 4;
    if (i >= total4) return;
    int o = (i * 4) / N_PTS;
    float a = ab[o], b = ab[64 + o];
    float4 v = ((float4*)out)[i];
    v.x = fmaxf(fmaf(v.x, a, b), 0.f);
    v.y = fmaxf(fmaf(v.y, a, b), 0.f);
    v.z = fmaxf(fmaf(v.z, a, b), 0.f);
    v.w = fmaxf(fmaf(v.w, a, b), 0.f);
    ((float4*)out)[i] = v;
}

// ================= fallback f32 path (small ws) =================
__global__ void k_wt_f32(const float* __restrict__ w, float* __restrict__ wtk) {
    int i = blockIdx.x * 256 + threadIdx.x;
    if (i >= K_NB * C_IN * C_OUT) return;
    int o = i & 63, r = i >> 6, c = r & 31, k = r >> 5;
    wtk[i] = w[(o * C_IN + c) * K_NB + k];
}

__launch_bounds__(256, 1)
__global__ void k_conv_f32(const float* __restrict__ src, const int* __restrict__ neigh,
                           const float* __restrict__ wtk, float* __restrict__ out) {
    __shared__ float wt_s[C_IN * C_OUT];
    const int lane = threadIdx.x & 63;
    const int wave = threadIdx.x >> 6;
    const int n0   = blockIdx.x * 64 + wave * 16;
    float acc[16];
#pragma unroll
    for (int p = 0; p < 16; ++p) acc[p] = 0.f;
    for (int k = 0; k < K_NB; ++k) {
        __syncthreads();
#pragma unroll
        for (int j = 0; j < 8; ++j)
            wt_s[threadIdx.x + j * 256] = wtk[k * (C_IN * C_OUT) + threadIdx.x + j * 256];
        __syncthreads();
        int t[16];
#pragma unroll
        for (int p = 0; p < 16; ++p) t[p] = neigh[(n0 + p) * K_NB + k];
#pragma unroll
        for (int c = 0; c < C_IN; ++c) {
            float wv = wt_s[c * C_OUT + lane];
#pragma unroll
            for (int p = 0; p < 16; ++p) {
                float xv = (t[p] >= 0) ? src[(long long)c * N_PTS + t[p]] : 0.f;
                acc[p] = fmaf(wv, xv, acc[p]);
            }
        }
    }
    float4* dst = (float4*)(out + (long long)lane * N_PTS + n0);
#pragma unroll
    for (int q = 0; q < 4; ++q) dst[q] = ((const float4*)acc)[q];
}

__global__ void k_stats1(const float* __restrict__ raw, float* __restrict__ ps) {
    int o = blockIdx.x & 63, sl = blockIdx.x >> 6;
    const int per = N_PTS / 8;
    const float4* row = (const float4*)(raw + (long long)o * N_PTS + (long long)sl * per);
    float s = 0.f, s2 = 0.f;
    for (int i = threadIdx.x; i < per / 4; i += 256) {
        float4 v = row[i];
        s  += v.x + v.y + v.z + v.w;
        s2 += v.x * v.x + v.y * v.y + v.z * v.z + v.w * v.w;
    }
#pragma unroll
    for (int off = 32; off > 0; off >>= 1) {
        s  += __shfl_down(s, off, 64);
        s2 += __shfl_down(s2, off, 64);
    }
    __shared__ float r0[4], r1[4];
    int wv = threadIdx.x >> 6;
    if ((threadIdx.x & 63) == 0) { r0[wv] = s; r1[wv] = s2; }
    __syncthreads();
    if (threadIdx.x == 0) {
        ps[blockIdx.x]       = r0[0] + r0[1] + r0[2] + r0[3];
        ps[512 + blockIdx.x] = r1[0] + r1[1] + r1[2] + r1[3];
    }
}

__global__ void k_stats2f(const float* __restrict__ ps, const float* __restrict__ gamma,
                          const float* __restrict__ beta, float* __restrict__ ab) {
    int o = threadIdx.x;
    float S = 0.f, S2 = 0.f;
#pragma unroll
    for (int sl = 0; sl < 8; ++sl) {
        S  += ps[sl * 64 + o];
        S2 += ps[512 + sl * 64 + o];
    }
    float mean = S / (float)N_PTS;
    float var  = S2 / (float)N_PTS - mean * mean;
    float a = gamma[o] * rsqrtf(var + BN_EPS);
    float b = beta[o] - mean * a;
    ab[o]      = a;
    ab[64 + o] = b;
}

extern "C" void kernel_launch(void* const* d_in, const int* in_sizes, int n_in,
                              void* d_out, int out_size, void* d_ws, size_t ws_size,
                              hipStream_t stream) {
    const float* x   = (const float*)d_in[0];
    const int*   nb  = (const int*)d_in[1];     // int64 in ref -> int32 on device
    const float* w   = (const float*)d_in[2];
    const float* gam = (const float*)d_in[3];
    const float* bet = (const float*)d_in[4];
    float* out = (float*)d_out;
    char* ws = (char*)d_ws;

    if (ws_size >= M_WS_NEED_B) {
        unsigned short* wt    = (unsigned short*)(ws + M_WT_OFF);
        float*          sums8 = (float*)(ws + M_SUM_OFF);
        unsigned*       cnt   = (unsigned*)(ws + M_CNT_OFF);
        float*          ab    = (float*)(ws + M_AB_OFF);
        unsigned short* xt    = (unsigned short*)(ws + M_XT_OFF);
        unsigned short* r16   = (unsigned short*)(ws + M_RAW_OFF);

        // zero the atomic banks + counter every launch (graph-replay safe)
        hipMemsetAsync(ws + M_SUM_OFF, 0, 4096 + 256 + 4, stream);
        k_prep<<<1006, 256, 0, stream>>>(x, w, xt, wt);

        if (ws_size >= M_WS_NEED_A) {
            k_conv_mfma<1><<<CBLK, 256, 0, stream>>>(xt, nb, wt, out, r16,
                                                     gam, bet, sums8, cnt, ab);
            k_norm16<<<(C_OUT * N_PTS / 8 + 255) / 256, 256, 0, stream>>>(r16, out, ab);
        } else {
            k_conv_mfma<0><<<CBLK, 256, 0, stream>>>(xt, nb, wt, out, r16,
                                                     gam, bet, sums8, cnt, ab);
            k_norm<<<((C_OUT * N_PTS) / 4 + 255) / 256, 256, 0, stream>>>(out, ab);
        }
    } else {
        float* wtk  = (float*)(ws + F_WTK_OFF);
        float* ab   = (float*)(ws + F_AB_OFF);
        float* ps   = (float*)(ws + F_PS_OFF);
        k_wt_f32<<<(K_NB * C_IN * C_OUT + 255) / 256, 256, 0, stream>>>(w, wtk);
        k_conv_f32<<<N_PTS / 64, 256, 0, stream>>>(x, nb, wtk, out);
        k_stats1<<<512, 256, 0, stream>>>(out, ps);
        k_stats2f<<<1, 64, 0, stream>>>(ps, gam, bet, ab);
        k_norm<<<((C_OUT * N_PTS) / 4 + 255) / 256, 256, 0, stream>>>(out, ab);
    }
}

// Round 13
// 123.395 us; speedup vs baseline: 4.1555x; 4.1555x over previous
//
#include <hip/hip_runtime.h>

#define N_PTS 200000
#define C_IN  32
#define C_OUT 64
#define K_NB  27
#define BN_EPS 1e-5f
#define CBLK  3125     // conv grid: 64 points per block

using bf16x8 = __attribute__((ext_vector_type(8))) short;
using f32x4  = __attribute__((ext_vector_type(4))) float;

typedef const __attribute__((address_space(1))) char GP;
typedef __attribute__((address_space(3))) char LP;

// ---------------- ws layout (MFMA paths) ----------------
//  [0, 114688)           wt  : bf16[28][64][32]  (row 27 zeros)
//  [114688, 115200)      ab  : float[128]
//  [131072, +1.6MB)      ps  : float[3125][128]  (per-block partial BN sums)
//  [2097152, +12.8MB)    xt  : bf16[N+1][32]     (row N = zeros)
//  [14897216, +25.6MB)   raw16 : fp16[64][N]     (config A only)
#define M_WT_OFF  0
#define M_AB_OFF  114688
#define M_PS_OFF  131072
#define M_XT_OFF  2097152
#define M_RAW_OFF 14897216
#define M_WS_NEED_B ((size_t)M_XT_OFF + (size_t)(N_PTS + 1) * C_IN * 2)          // 14,897,216
#define M_WS_NEED_A ((size_t)M_RAW_OFF + (size_t)C_OUT * N_PTS * 2)              // 40,497,216

// ---------------- ws layout (fallback f32 path) ----------------
#define F_WTK_OFF 0
#define F_AB_OFF  221184
#define F_PS_OFF  221824

__device__ __forceinline__ unsigned short f2bf(float f) {
    unsigned int u = __float_as_uint(f);
    u = (u + 0x7fffu + ((u >> 16) & 1u)) >> 16;
    return (unsigned short)u;
}
__device__ __forceinline__ unsigned short f2h(float f) {
    _Float16 h = (_Float16)f;
    unsigned short u; __builtin_memcpy(&u, &h, 2); return u;
}
__device__ __forceinline__ float h2f(unsigned short u) {
    _Float16 h; __builtin_memcpy(&h, &u, 2); return (float)h;
}

// ---------- prep: blocks [0,782): x->xt bf16 (+zero row); [782,1006): w->wt ----------
__global__ void k_prep(const float* __restrict__ x, const float* __restrict__ w,
                       unsigned short* __restrict__ xt, unsigned short* __restrict__ wt) {
    if (blockIdx.x < 782) {
        int n = blockIdx.x * 256 + threadIdx.x;
        if (n > N_PTS) return;
        unsigned short row[C_IN];
        if (n == N_PTS) {
#pragma unroll
            for (int c = 0; c < C_IN; ++c) row[c] = 0;
        } else {
#pragma unroll
            for (int c = 0; c < C_IN; ++c) row[c] = f2bf(x[(long long)c * N_PTS + n]);
        }
        uint4* dst = (uint4*)(xt + (long long)n * C_IN);
#pragma unroll
        for (int q = 0; q < 4; ++q) dst[q] = ((const uint4*)row)[q];
    } else {
        int i = (blockIdx.x - 782) * 256 + threadIdx.x;
        if (i >= 28 * C_OUT * C_IN) return;
        int c = i & 31, o = (i >> 5) & 63, k = i >> 11;
        wt[i] = (k < K_NB) ? f2bf(w[(o * C_IN + c) * K_NB + k]) : (unsigned short)0;
    }
}

// ---------- conv: 64 pts/block, och-split waves, LDS B-ring, asm counted-vmcnt pipeline ----------
// RAW16=1: store raw conv output as fp16 into raw16[]; RAW16=0: f32 into out[] (R7-exact).
template <int RAW16>
__launch_bounds__(256, 5)
__global__ void k_conv_mfma(const unsigned short* __restrict__ xt,
                            const int* __restrict__ neigh,
                            const unsigned short* __restrict__ wt,
                            float* __restrict__ out,
                            unsigned short* __restrict__ raw16,
                            float* __restrict__ ps) {
    __shared__ __align__(16) char lds_raw[6 * 4096 + K_NB * 64 * 4];
    char* bufB = lds_raw;
    int*  ntb  = (int*)(lds_raw + 24576);

    const int lane = threadIdx.x & 63;
    const int w    = threadIdx.x >> 6;          // wave id = och-quarter = staging g-group
    const int l15  = lane & 15, lq = lane >> 4;
    const int n0   = blockIdx.x * 64;

    // ---- preload this block's neighbor indices into LDS (validity-remapped) ----
    {
        int p  = threadIdx.x & 63;
        int kb = (threadIdx.x >> 6) * 7;        // 0,7,14,21
        const int* nrow = neigh + (long long)(n0 + p) * K_NB;
#pragma unroll
        for (int i = 0; i < 7; ++i) {
            int kk = kb + i;
            if (kk < K_NB) {
                int t = nrow[kk];
                ntb[kk * 64 + p] = ((unsigned)t < N_PTS) ? t : N_PTS;
            }
        }
    }
    __syncthreads();

    const char* xtb = (const char*)xt;                              // 64B rows
    const unsigned short* wtA = wt + w * 512 + l15 * 32 + lq * 8;   // + k*2048
    const unsigned qoff = (unsigned)(lq * 16);

    unsigned bufB_a = (unsigned)(unsigned long long)(LP*)lds_raw;
    unsigned ntb_a  = bufB_a + 24576;
    unsigned badr   = bufB_a + (unsigned)(lq * 256 + l15 * 16);     // + slot*4096 + g*1024 (imm)
    unsigned tadr   = ntb_a + (unsigned)(w * 64 + l15 * 4);         // + k*256 (imm)

    f32x4 acc0 = {0.f,0.f,0.f,0.f}, acc1 = {0.f,0.f,0.f,0.f},
          acc2 = {0.f,0.f,0.f,0.f}, acc3 = {0.f,0.f,0.f,0.f};
    bf16x8 Ar[4];
    int tcur;

    // ---- prologue: stage k=0..3 + A(0..3); leave t(4) pending ----
#define PSTEP(KK) \
    asm volatile("ds_read_b32 %0, %1 offset:%2" : "=v"(tcur) : "v"(tadr), "i"((KK)*256)); \
    asm volatile("s_waitcnt lgkmcnt(0)" ::: "memory"); \
    __builtin_amdgcn_sched_barrier(0); \
    __builtin_amdgcn_global_load_lds((GP*)(xtb + (unsigned long long)(unsigned)tcur * 64ull + qoff), \
        (LP*)(bufB + (KK)*4096 + w*1024), 16, 0, 0); \
    asm volatile("global_load_dwordx4 %0, %1, off" : "=v"(Ar[(KK)&3]) : "v"(wtA + (KK)*2048)); \
    __builtin_amdgcn_sched_barrier(0);

    PSTEP(0) PSTEP(1) PSTEP(2) PSTEP(3)
#undef PSTEP
    asm volatile("ds_read_b32 %0, %1 offset:%2" : "=v"(tcur) : "v"(tadr), "i"(4*256));

    // ---- main loop, fully unrolled; 2 VMEM/iter, vmcnt counted, raw barrier ----
#define STEP(K, VM, PF, NT, LG) { \
    if (PF) { \
        asm volatile("s_waitcnt lgkmcnt(0)" ::: "memory"); \
        __builtin_amdgcn_sched_barrier(0); \
        __builtin_amdgcn_global_load_lds((GP*)(xtb + (unsigned long long)(unsigned)tcur * 64ull + qoff), \
            (LP*)(bufB + (((K)+4)%6)*4096 + w*1024), 16, 0, 0); \
    } \
    __builtin_amdgcn_sched_barrier(0); \
    asm volatile("s_waitcnt vmcnt(%0)" :: "i"(VM) : "memory"); \
    __builtin_amdgcn_sched_barrier(0); \
    asm volatile("s_barrier" ::: "memory"); \
    __builtin_amdgcn_sched_barrier(0); \
    bf16x8 b0, b1, b2, b3; \
    asm volatile("ds_read_b128 %0, %1 offset:%2" : "=v"(b0) : "v"(badr), "i"(((K)%6)*4096 + 0)); \
    asm volatile("ds_read_b128 %0, %1 offset:%2" : "=v"(b1) : "v"(badr), "i"(((K)%6)*4096 + 1024)); \
    asm volatile("ds_read_b128 %0, %1 offset:%2" : "=v"(b2) : "v"(badr), "i"(((K)%6)*4096 + 2048)); \
    asm volatile("ds_read_b128 %0, %1 offset:%2" : "=v"(b3) : "v"(badr), "i"(((K)%6)*4096 + 3072)); \
    if (NT) { asm volatile("ds_read_b32 %0, %1 offset:%2" : "=v"(tcur) : "v"(tadr), "i"(((K)+5)*256)); } \
    asm volatile("s_waitcnt lgkmcnt(%0)" :: "i"(LG) : "memory"); \
    __builtin_amdgcn_sched_barrier(0); \
    acc0 = __builtin_amdgcn_mfma_f32_16x16x32_bf16(Ar[(K)&3], b0, acc0, 0, 0, 0); \
    acc1 = __builtin_amdgcn_mfma_f32_16x16x32_bf16(Ar[(K)&3], b1, acc1, 0, 0, 0); \
    acc2 = __builtin_amdgcn_mfma_f32_16x16x32_bf16(Ar[(K)&3], b2, acc2, 0, 0, 0); \
    acc3 = __builtin_amdgcn_mfma_f32_16x16x32_bf16(Ar[(K)&3], b3, acc3, 0, 0, 0); \
    if (PF) { \
        asm volatile("global_load_dwordx4 %0, %1, off" : "=v"(Ar[((K)+4)&3]) : "v"(wtA + ((K)+4)*2048)); \
    } \
    __builtin_amdgcn_sched_barrier(0); \
}

    STEP(0,7,1,1,1)  STEP(1,7,1,1,1)  STEP(2,7,1,1,1)  STEP(3,7,1,1,1)
    STEP(4,7,1,1,1)  STEP(5,7,1,1,1)  STEP(6,7,1,1,1)  STEP(7,7,1,1,1)
    STEP(8,7,1,1,1)  STEP(9,7,1,1,1)  STEP(10,7,1,1,1) STEP(11,7,1,1,1)
    STEP(12,7,1,1,1) STEP(13,7,1,1,1) STEP(14,7,1,1,1) STEP(15,7,1,1,1)
    STEP(16,7,1,1,1) STEP(17,7,1,1,1) STEP(18,7,1,1,1) STEP(19,7,1,1,1)
    STEP(20,7,1,1,1) STEP(21,7,1,1,1) STEP(22,7,1,0,0)
    STEP(23,6,0,0,0) STEP(24,4,0,0,0) STEP(25,2,0,0,0) STEP(26,0,0,0,0)
#undef STEP

    asm volatile("s_waitcnt vmcnt(0) lgkmcnt(0)" ::: "memory");
    __builtin_amdgcn_sched_barrier(0);

    // ---- raw output: och = 16w + lq*4 + r, point = n0 + g*16 + l15 ----
    if (RAW16) {
#pragma unroll
        for (int r = 0; r < 4; ++r) {
            unsigned short* o = raw16 + (long long)(16 * w + lq * 4 + r) * N_PTS + n0 + l15;
            o[0]  = f2h(acc0[r]);
            o[16] = f2h(acc1[r]);
            o[32] = f2h(acc2[r]);
            o[48] = f2h(acc3[r]);
        }
    } else {
#pragma unroll
        for (int r = 0; r < 4; ++r) {
            float* o = out + (long long)(16 * w + lq * 4 + r) * N_PTS + n0 + l15;
            o[0]  = acc0[r];
            o[16] = acc1[r];
            o[32] = acc2[r];
            o[48] = acc3[r];
        }
    }

    // ---- fused BN partials: sum over this block's 64 points per och (exact f32) ----
    f32x4 s  = acc0 + acc1 + acc2 + acc3;
    f32x4 sq = acc0 * acc0 + acc1 * acc1 + acc2 * acc2 + acc3 * acc3;
#pragma unroll
    for (int d = 1; d < 16; d <<= 1) {
#pragma unroll
        for (int r = 0; r < 4; ++r) {
            s[r]  += __shfl_xor(s[r], d);
            sq[r] += __shfl_xor(sq[r], d);
        }
    }
    if (l15 == 0) {
#pragma unroll
        for (int r = 0; r < 4; ++r) {
            int ch = 16 * w + lq * 4 + r;
            ps[blockIdx.x * 128 + ch]      = s[r];
            ps[blockIdx.x * 128 + 64 + ch] = sq[r];
        }
    }
}

// ---------- reduce per-block partials -> a,b ----------
__global__ void k_stats2(const float* __restrict__ ps, const float* __restrict__ gamma,
                         const float* __restrict__ beta, float* __restrict__ ab) {
    int ch = blockIdx.x;   // 64 blocks
    float s = 0.f, s2 = 0.f;
    for (int b = threadIdx.x; b < CBLK; b += 256) {
        s  += ps[b * 128 + ch];
        s2 += ps[b * 128 + 64 + ch];
    }
#pragma unroll
    for (int off = 32; off > 0; off >>= 1) {
        s  += __shfl_down(s, off, 64);
        s2 += __shfl_down(s2, off, 64);
    }
    __shared__ float r0[4], r1[4];
    int wv = threadIdx.x >> 6;
    if ((threadIdx.x & 63) == 0) { r0[wv] = s; r1[wv] = s2; }
    __syncthreads();
    if (threadIdx.x == 0) {
        float S  = r0[0] + r0[1] + r0[2] + r0[3];
        float S2 = r1[0] + r1[1] + r1[2] + r1[3];
        float mean = S / (float)N_PTS;
        float var  = S2 / (float)N_PTS - mean * mean;
        float a = gamma[ch] * rsqrtf(var + BN_EPS);
        float b = beta[ch] - mean * a;
        ab[ch]      = a;
        ab[64 + ch] = b;
    }
}

// ---------- normalize + relu from fp16 raw -> f32 out (config A) ----------
__global__ void k_norm16(const unsigned short* __restrict__ raw16, float* __restrict__ out,
                         const float* __restrict__ ab) {
    int i = blockIdx.x * 256 + threadIdx.x;        // ushort8 units
    const int tot8 = (C_OUT * N_PTS) / 8;          // 1,600,000
    if (i >= tot8) return;
    int o = (int)(((long long)i * 8) / N_PTS);
    float a = ab[o], b = ab[64 + o];
    union { uint4 u4; unsigned short us[8]; } U;
    U.u4 = ((const uint4*)raw16)[i];
    float4 r0, r1;
    r0.x = fmaxf(fmaf(h2f(U.us[0]), a, b), 0.f);
    r0.y = fmaxf(fmaf(h2f(U.us[1]), a, b), 0.f);
    r0.z = fmaxf(fmaf(h2f(U.us[2]), a, b), 0.f);
    r0.w = fmaxf(fmaf(h2f(U.us[3]), a, b), 0.f);
    r1.x = fmaxf(fmaf(h2f(U.us[4]), a, b), 0.f);
    r1.y = fmaxf(fmaf(h2f(U.us[5]), a, b), 0.f);
    r1.z = fmaxf(fmaf(h2f(U.us[6]), a, b), 0.f);
    r1.w = fmaxf(fmaf(h2f(U.us[7]), a, b), 0.f);
    ((float4*)out)[2 * i]     = r0;
    ((float4*)out)[2 * i + 1] = r1;
}

// ---------- normalize + relu, in place on d_out (config B) ----------
__global__ void k_norm(float* __restrict__ out, const float* __restrict__ ab) {
    int i = blockIdx.x * 256 + threadIdx.x;
    const int total4 = (C_OUT * N_PTS) / 4;
    if (i >= total4) return;
    int o = (i * 4) / N_PTS;
    float a = ab[o], b = ab[64 + o];
    float4 v = ((float4*)out)[i];
    v.x = fmaxf(fmaf(v.x, a, b), 0.f);
    v.y = fmaxf(fmaf(v.y, a, b), 0.f);
    v.z = fmaxf(fmaf(v.z, a, b), 0.f);
    v.w = fmaxf(fmaf(v.w, a, b), 0.f);
    ((float4*)out)[i] = v;
}

// ================= fallback f32 path (small ws) =================
__global__ void k_wt_f32(const float* __restrict__ w, float* __restrict__ wtk) {
    int i = blockIdx.x * 256 + threadIdx.x;
    if (i >= K_NB * C_IN * C_OUT) return;
    int o = i & 63, r = i >> 6, c = r & 31, k = r >> 5;
    wtk[i] = w[(o * C_IN + c) * K_NB + k];
}

__launch_bounds__(256, 1)
__global__ void k_conv_f32(const float* __restrict__ src, const int* __restrict__ neigh,
                           const float* __restrict__ wtk, float* __restrict__ out) {
    __shared__ float wt_s[C_IN * C_OUT];
    const int lane = threadIdx.x & 63;
    const int wave = threadIdx.x >> 6;
    const int n0   = blockIdx.x * 64 + wave * 16;
    float acc[16];
#pragma unroll
    for (int p = 0; p < 16; ++p) acc[p] = 0.f;
    for (int k = 0; k < K_NB; ++k) {
        __syncthreads();
#pragma unroll
        for (int j = 0; j < 8; ++j)
            wt_s[threadIdx.x + j * 256] = wtk[k * (C_IN * C_OUT) + threadIdx.x + j * 256];
        __syncthreads();
        int t[16];
#pragma unroll
        for (int p = 0; p < 16; ++p) t[p] = neigh[(n0 + p) * K_NB + k];
#pragma unroll
        for (int c = 0; c < C_IN; ++c) {
            float wv = wt_s[c * C_OUT + lane];
#pragma unroll
            for (int p = 0; p < 16; ++p) {
                float xv = (t[p] >= 0) ? src[(long long)c * N_PTS + t[p]] : 0.f;
                acc[p] = fmaf(wv, xv, acc[p]);
            }
        }
    }
    float4* dst = (float4*)(out + (long long)lane * N_PTS + n0);
#pragma unroll
    for (int q = 0; q < 4; ++q) dst[q] = ((const float4*)acc)[q];
}

__global__ void k_stats1(const float* __restrict__ raw, float* __restrict__ ps) {
    int o = blockIdx.x & 63, sl = blockIdx.x >> 6;
    const int per = N_PTS / 8;
    const float4* row = (const float4*)(raw + (long long)o * N_PTS + (long long)sl * per);
    float s = 0.f, s2 = 0.f;
    for (int i = threadIdx.x; i < per / 4; i += 256) {
        float4 v = row[i];
        s  += v.x + v.y + v.z + v.w;
        s2 += v.x * v.x + v.y * v.y + v.z * v.z + v.w * v.w;
    }
#pragma unroll
    for (int off = 32; off > 0; off >>= 1) {
        s  += __shfl_down(s, off, 64);
        s2 += __shfl_down(s2, off, 64);
    }
    __shared__ float r0[4], r1[4];
    int wv = threadIdx.x >> 6;
    if ((threadIdx.x & 63) == 0) { r0[wv] = s; r1[wv] = s2; }
    __syncthreads();
    if (threadIdx.x == 0) {
        ps[blockIdx.x]       = r0[0] + r0[1] + r0[2] + r0[3];
        ps[512 + blockIdx.x] = r1[0] + r1[1] + r1[2] + r1[3];
    }
}

__global__ void k_stats2f(const float* __restrict__ ps, const float* __restrict__ gamma,
                          const float* __restrict__ beta, float* __restrict__ ab) {
    int o = threadIdx.x;
    float S = 0.f, S2 = 0.f;
#pragma unroll
    for (int sl = 0; sl < 8; ++sl) {
        S  += ps[sl * 64 + o];
        S2 += ps[512 + sl * 64 + o];
    }
    float mean = S / (float)N_PTS;
    float var  = S2 / (float)N_PTS - mean * mean;
    float a = gamma[o] * rsqrtf(var + BN_EPS);
    float b = beta[o] - mean * a;
    ab[o]      = a;
    ab[64 + o] = b;
}

extern "C" void kernel_launch(void* const* d_in, const int* in_sizes, int n_in,
                              void* d_out, int out_size, void* d_ws, size_t ws_size,
                              hipStream_t stream) {
    const float* x   = (const float*)d_in[0];
    const int*   nb  = (const int*)d_in[1];     // int64 in ref -> int32 on device
    const float* w   = (const float*)d_in[2];
    const float* gam = (const float*)d_in[3];
    const float* bet = (const float*)d_in[4];
    float* out = (float*)d_out;
    char* ws = (char*)d_ws;

    if (ws_size >= M_WS_NEED_B) {
        unsigned short* wt  = (unsigned short*)(ws + M_WT_OFF);
        float*          ab  = (float*)(ws + M_AB_OFF);
        float*          ps  = (float*)(ws + M_PS_OFF);
        unsigned short* xt  = (unsigned short*)(ws + M_XT_OFF);
        unsigned short* r16 = (unsigned short*)(ws + M_RAW_OFF);

        k_prep<<<1006, 256, 0, stream>>>(x, w, xt, wt);
        if (ws_size >= M_WS_NEED_A) {
            // config A: fp16 raw intermediate (half the conv-write + half the norm-read bytes)
            k_conv_mfma<1><<<CBLK, 256, 0, stream>>>(xt, nb, wt, out, r16, ps);
            k_stats2<<<C_OUT, 256, 0, stream>>>(ps, gam, bet, ab);
            k_norm16<<<(C_OUT * N_PTS / 8 + 255) / 256, 256, 0, stream>>>(r16, out, ab);
        } else {
            // config B: R7-exact (f32 raw in d_out, normalize in place)
            k_conv_mfma<0><<<CBLK, 256, 0, stream>>>(xt, nb, wt, out, r16, ps);
            k_stats2<<<C_OUT, 256, 0, stream>>>(ps, gam, bet, ab);
            k_norm<<<((C_OUT * N_PTS) / 4 + 255) / 256, 256, 0, stream>>>(out, ab);
        }
    } else {
        float* wtk  = (float*)(ws + F_WTK_OFF);
        float* ab   = (float*)(ws + F_AB_OFF);
        float* ps   = (float*)(ws + F_PS_OFF);
        k_wt_f32<<<(K_NB * C_IN * C_OUT + 255) / 256, 256, 0, stream>>>(w, wtk);
        k_conv_f32<<<N_PTS / 64, 256, 0, stream>>>(x, nb, wtk, out);
        k_stats1<<<512, 256, 0, stream>>>(out, ps);
        k_stats2f<<<1, 64, 0, stream>>>(ps, gam, bet, ab);
        k_norm<<<((C_OUT * N_PTS) / 4 + 255) / 256, 256, 0, stream>>>(out, ab);
    }
}